// Round 2
// baseline (850.223 us; speedup 1.0000x reference)
//
#include <hip/hip_runtime.h>
#include <hip/hip_bf16.h>

#define N_NODESC 50000
#define N_EDGESC 1600000
#define SDIM 64
#define VDIM 32
#define HID 96
#define IN_DIMC 163
#define NTILES (N_EDGESC / 16)

typedef float f32x4 __attribute__((ext_vector_type(4)));
typedef short s16x8 __attribute__((ext_vector_type(8)));

__device__ __forceinline__ float bf2f(__hip_bfloat16 x) { return __bfloat162float(x); }
__device__ __forceinline__ __hip_bfloat16 f2bf(float x) { return __float2bfloat16(x); }

__device__ __forceinline__ short f2bfbits(float x) {
    union { __hip_bfloat16 h; short s; } u;
    u.h = __float2bfloat16(x);
    return u.s;
}
__device__ __forceinline__ float bfs2f(short s) {
    return __uint_as_float(((unsigned)(unsigned short)s) << 16);
}

// ---------------------------------------------------------------------------
// Detect whether edge_index arrived as int64 (odd int32 words all zero) or int32.
__global__ void detect_kernel(const int* __restrict__ ei, int* __restrict__ flag) {
    int t = threadIdx.x;
    int v = (ei[2 * t + 1] == 0) ? 1 : 0;
    unsigned long long b = __ballot(v);
    if (t == 0) *flag = (b == 0xFFFFFFFFFFFFFFFFULL) ? 1 : 0;
}

// ---------------------------------------------------------------------------
// Init out with the residual (h_scalar | h_vector); atomics accumulate on top.
__global__ void init_out(const float* __restrict__ hs, const float* __restrict__ hv,
                         float* __restrict__ out) {
    int i = blockIdx.x * blockDim.x + threadIdx.x;
    if (i >= N_NODESC * (SDIM + VDIM)) return;
    out[i] = (i < N_NODESC * SDIM) ? hs[i] : hv[i - N_NODESC * SDIM];
}

// ---------------------------------------------------------------------------
// Per-node tables, 8 nodes/block with register reuse of W1 (8x less W1 traffic).
// T1[n][3][96] = {P, U, V} row-interleaved (src-indexed tables together);
// T2[n][96]    = Q (dst-indexed).
// P = hs@W1[0:64] + b1, Q = hs@W1[64:128], U = hv@W1c, V = hv@W1c'(swap/negate).
__global__ __launch_bounds__(192) void node_precompute(
    const float* __restrict__ hs, const float* __restrict__ hv,
    const float* __restrict__ W1, const float* __restrict__ b1,
    __hip_bfloat16* __restrict__ T1, __hip_bfloat16* __restrict__ T2) {
    __shared__ float s_x[8][96];  // per node: [0:64]=hs, [64:96]=hv
    const int b = blockIdx.x, t = threadIdx.x;
    const int base = b * 8;
    for (int i = t; i < 8 * 96; i += 192) {
        int p = i / 96, c = i - p * 96;
        s_x[p][c] = (c < 64) ? hs[(base + p) * 64 + c] : hv[(base + p) * 32 + (c - 64)];
    }
    __syncthreads();
    const int j = t % 96;
    const int half = t / 96;  // 0 or 1 -> nodes half*4 .. half*4+3
    float pr_[4], qr[4], ur[4], vr[4];
    float bj = b1[j];
    #pragma unroll
    for (int i = 0; i < 4; ++i) { pr_[i] = bj; qr[i] = 0.f; ur[i] = 0.f; vr[i] = 0.f; }
    for (int k = 0; k < 64; ++k) {
        float wp = W1[k * HID + j];
        float wq = W1[(64 + k) * HID + j];
        #pragma unroll
        for (int i = 0; i < 4; ++i) {
            float x = s_x[half * 4 + i][k];
            pr_[i] += x * wp;
            qr[i] += x * wq;
        }
    }
    for (int pr = 0; pr < 16; ++pr) {
        float wa = W1[(128 + 2 * pr) * HID + j];
        float wb = W1[(129 + 2 * pr) * HID + j];
        #pragma unroll
        for (int i = 0; i < 4; ++i) {
            float x = s_x[half * 4 + i][64 + 2 * pr];
            float y = s_x[half * 4 + i][65 + 2 * pr];
            ur[i] += x * wa + y * wb;
            vr[i] += x * wb - y * wa;
        }
    }
    #pragma unroll
    for (int i = 0; i < 4; ++i) {
        int n = base + half * 4 + i;
        T1[n * 288 + j]       = f2bf(pr_[i]);
        T1[n * 288 + 96 + j]  = f2bf(ur[i]);
        T1[n * 288 + 192 + j] = f2bf(vr[i]);
        T2[n * 96 + j]        = f2bf(qr[i]);
    }
}

// ---------------------------------------------------------------------------
// Main edge kernel. One WAVE owns a 16-edge tile; no barriers in the loop.
// Phase 1 computed directly in MFMA A-fragment layout (h never touches LDS).
__global__ __launch_bounds__(256, 4) void edge_kernel(
    const int* __restrict__ ei, const float* __restrict__ pos,
    const float* __restrict__ ori, const float* __restrict__ W1,
    const float* __restrict__ W2, const float* __restrict__ b2,
    const __hip_bfloat16* __restrict__ T1, const __hip_bfloat16* __restrict__ T2,
    const int* __restrict__ flag64, float* __restrict__ out) {
    __shared__ short sW2[18 * 64 * 8];  // W2 B-frags pre-swizzled: [nt*3+kt][lane][8]
    __shared__ short sGW[36 * 8];       // geo-weight frags bf16: [kt*12 + r*4 + q][8]

    const int t = threadIdx.x;
    const int lane = t & 63;
    const int w = t >> 6;
    const int m16 = lane & 15;
    const int q = lane >> 4;

    // One-time: stage W2 B-fragments (frag element: B[k=kt*32+q*8+i][n=nt*16+m16])
    for (int sI = t; sI < 18 * 64; sI += 256) {
        int f = sI >> 6, l = sI & 63;
        int n = (f / 3) * 16 + (l & 15);
        int k0 = (f % 3) * 32 + (l >> 4) * 8;
        s16x8 v;
        #pragma unroll
        for (int i = 0; i < 8; ++i) v[i] = f2bfbits(W2[(k0 + i) * HID + n]);
        *(s16x8*)&sW2[sI * 8] = v;
    }
    // One-time: stage geo weight fragments (W1 rows 160..162), bf16
    for (int sI = t; sI < 36; sI += 256) {
        int kt = sI / 12, rr = (sI % 12) / 4, qq = sI % 4;
        #pragma unroll
        for (int i = 0; i < 8; ++i)
            sGW[sI * 8 + i] = f2bfbits(W1[(160 + rr) * HID + kt * 32 + qq * 8 + i]);
    }
    __syncthreads();

    float b2v[6];
    #pragma unroll
    for (int nt = 0; nt < 6; ++nt) b2v[nt] = b2[nt * 16 + m16];

    const bool i64 = (*flag64 != 0);
    const long long* ei64 = (const long long*)ei;

    for (int tile = blockIdx.x * 4 + w; tile < NTILES; tile += gridDim.x * 4) {
        const int e = tile * 16 + m16;
        int sN, dN;
        if (i64) { sN = (int)ei64[e]; dN = (int)ei64[N_EDGESC + e]; }
        else     { sN = ei[e];        dN = ei[N_EDGESC + e]; }

        // Geometry for edge m16 (computed redundantly by the 4 lane-groups).
        float ca, sa, cb, sb;
        __sincosf(2.0f * ori[dN], &sa, &ca);
        __sincosf(2.0f * ori[sN], &sb, &cb);
        float c = cb * ca + sb * sa;   // cos(2(beta-alpha))
        float s = sb * ca - cb * sa;   // sin(2(beta-alpha))
        float2 ps = *(const float2*)&pos[2 * sN];
        float2 pd = *(const float2*)&pos[2 * dN];
        float dx = ps.x - pd.x, dy = ps.y - pd.y;
        float d2 = dx * dx + dy * dy;
        float d = sqrtf(d2) + 1e-6f;
        float c2f = 1.0f, s2f = 0.0f;
        if (d2 > 0.f) {
            float inv = 1.0f / d2;
            c2f = (dx * dx - dy * dy) * inv;  // cos(2phi)
            s2f = 2.0f * dx * dy * inv;       // sin(2phi)
        }
        float cg = c2f * ca + s2f * sa;  // cos(2phi-2alpha)
        float sg = s2f * ca - c2f * sa;  // sin(2phi-2alpha)

        // Phase 1 directly into A-frag layout: h[edge=m16][j=kt*32+q*8+i]
        const s16x8* t1s = (const s16x8*)&T1[sN * 288];
        s16x8 afr[3];
        #pragma unroll
        for (int kt = 0; kt < 3; ++kt) {
            int jv = kt * 4 + q;                 // (kt*32+q*8)/8
            s16x8 Pv = t1s[jv];
            s16x8 Uv = t1s[12 + jv];
            s16x8 Vv = t1s[24 + jv];
            s16x8 Qv = *(const s16x8*)&T2[dN * 96 + kt * 32 + q * 8];
            s16x8 w0 = *(const s16x8*)&sGW[(kt * 12 + q) * 8];
            s16x8 w1r = *(const s16x8*)&sGW[(kt * 12 + 4 + q) * 8];
            s16x8 w2r = *(const s16x8*)&sGW[(kt * 12 + 8 + q) * 8];
            s16x8 hv8;
            #pragma unroll
            for (int i = 0; i < 8; ++i) {
                float pre = bfs2f(Pv[i]) + bfs2f(Qv[i])
                          + c * bfs2f(Uv[i]) + s * bfs2f(Vv[i])
                          + d * bfs2f(w0[i]) + cg * bfs2f(w1r[i]) + sg * bfs2f(w2r[i]);
                float h = pre * __builtin_amdgcn_rcpf(1.0f + __expf(-pre));
                hv8[i] = f2bfbits(h);
            }
            afr[kt] = hv8;
        }

        // Layer 2 via MFMA, B-frags from LDS (conflict-free ds_read_b128).
        f32x4 acc[6];
        #pragma unroll
        for (int nt = 0; nt < 6; ++nt) acc[nt] = (f32x4){0.f, 0.f, 0.f, 0.f};
        #pragma unroll
        for (int nt = 0; nt < 6; ++nt)
            #pragma unroll
            for (int kt = 0; kt < 3; ++kt) {
                s16x8 bf = *(const s16x8*)&sW2[((nt * 3 + kt) * 64 + lane) * 8];
                acc[nt] = __builtin_amdgcn_mfma_f32_16x16x32_bf16(afr[kt], bf, acc[nt], 0, 0, 0);
            }

        // Epilogue + scatter. C/D: col(n)=lane&15, row(edge)=q*4+r.
        int dsts[4];
        #pragma unroll
        for (int r = 0; r < 4; ++r) dsts[r] = __shfl(dN, q * 4 + r, 64);
        #pragma unroll
        for (int nt = 0; nt < 6; ++nt) {
            int u = nt * 16 + m16;
            #pragma unroll
            for (int r = 0; r < 4; ++r) {
                float val = acc[nt][r] + b2v[nt];
                if (nt < 4) atomicAdd(&out[dsts[r] * SDIM + u], val);
                else atomicAdd(&out[N_NODESC * SDIM + dsts[r] * VDIM + (u - SDIM)], val);
            }
        }
    }
}

// ---------------------------------------------------------------------------
// Fallback (used only if ws too small for tables): fully per-edge, correct but slow.
__global__ __launch_bounds__(192) void edge_fallback(
    const int* __restrict__ ei, const float* __restrict__ hs,
    const float* __restrict__ hv, const float* __restrict__ pos,
    const float* __restrict__ ori, const float* __restrict__ W1,
    const float* __restrict__ b1, const float* __restrict__ W2,
    const float* __restrict__ b2, const int* __restrict__ flag64,
    float* __restrict__ out) {
    __shared__ float s_msg[IN_DIMC];
    __shared__ float s_h[HID];
    int e = blockIdx.x;
    int t = threadIdx.x;
    const bool i64 = (*flag64 != 0);
    int sN, dN;
    if (i64) {
        const long long* e64 = (const long long*)ei;
        sN = (int)e64[e]; dN = (int)e64[N_EDGESC + e];
    } else { sN = ei[e]; dN = ei[N_EDGESC + e]; }

    if (t < IN_DIMC) {
        if (t < 64) s_msg[t] = hs[sN * SDIM + t];
        else if (t < 128) s_msg[t] = hs[dN * SDIM + (t - 64)];
        else {
            float ca, sa, cb, sb;
            __sincosf(2.0f * ori[dN], &sa, &ca);
            __sincosf(2.0f * ori[sN], &sb, &cb);
            float c = cb * ca + sb * sa;
            float s = sb * ca - cb * sa;
            float dx = pos[2 * sN] - pos[2 * dN];
            float dy = pos[2 * sN + 1] - pos[2 * dN + 1];
            float d2 = dx * dx + dy * dy;
            if (t < 160) {
                int pr = (t - 128) >> 1;
                float x = hv[sN * VDIM + 2 * pr], y = hv[sN * VDIM + 2 * pr + 1];
                s_msg[t] = ((t & 1) == 0) ? (c * x - s * y) : (s * x + c * y);
            } else if (t == 160) s_msg[t] = sqrtf(d2) + 1e-6f;
            else {
                float c2f = 1.0f, s2f = 0.0f;
                if (d2 > 0.f) {
                    float inv = 1.0f / d2;
                    c2f = (dx * dx - dy * dy) * inv;
                    s2f = 2.0f * dx * dy * inv;
                }
                s_msg[t] = (t == 161) ? (c2f * ca + s2f * sa) : (s2f * ca - c2f * sa);
            }
        }
    }
    __syncthreads();
    if (t < HID) {
        float a = b1[t];
        for (int k = 0; k < IN_DIMC; ++k) a += s_msg[k] * W1[k * HID + t];
        s_h[t] = a / (1.0f + __expf(-a));
    }
    __syncthreads();
    if (t < HID) {
        float a = b2[t];
        for (int k = 0; k < HID; ++k) a += s_h[k] * W2[k * HID + t];
        if (t < SDIM) atomicAdd(&out[dN * SDIM + t], a);
        else atomicAdd(&out[N_NODESC * SDIM + dN * VDIM + (t - SDIM)], a);
    }
}

// ---------------------------------------------------------------------------
extern "C" void kernel_launch(void* const* d_in, const int* in_sizes, int n_in,
                              void* d_out, int out_size, void* d_ws, size_t ws_size,
                              hipStream_t stream) {
    const float* hs  = (const float*)d_in[0];
    const float* hv  = (const float*)d_in[1];
    const int*   ei  = (const int*)d_in[2];
    const float* pos = (const float*)d_in[3];
    const float* ori = (const float*)d_in[4];
    const float* W1  = (const float*)d_in[5];
    const float* b1  = (const float*)d_in[6];
    const float* W2  = (const float*)d_in[7];
    const float* b2  = (const float*)d_in[8];
    float* out = (float*)d_out;

    const size_t T1B = (size_t)N_NODESC * 288 * sizeof(__hip_bfloat16);  // 28.8 MB
    const size_t T2B = (size_t)N_NODESC * 96 * sizeof(__hip_bfloat16);   //  9.6 MB
    const bool big = ws_size >= T1B + T2B + 16;

    init_out<<<(N_NODESC * (SDIM + VDIM) + 255) / 256, 256, 0, stream>>>(hs, hv, out);

    if (big) {
        char* ws = (char*)d_ws;
        __hip_bfloat16* T1 = (__hip_bfloat16*)(ws);
        __hip_bfloat16* T2 = (__hip_bfloat16*)(ws + T1B);
        int* flag = (int*)(ws + T1B + T2B);
        detect_kernel<<<1, 64, 0, stream>>>(ei, flag);
        node_precompute<<<N_NODESC / 8, 192, 0, stream>>>(hs, hv, W1, b1, T1, T2);
        edge_kernel<<<2500, 256, 0, stream>>>(ei, pos, ori, W1, W2, b2,
                                              T1, T2, flag, out);
    } else {
        int* flag = (int*)d_ws;
        detect_kernel<<<1, 64, 0, stream>>>(ei, flag);
        edge_fallback<<<N_EDGESC, 192, 0, stream>>>(ei, hs, hv, pos, ori, W1, b1,
                                                    W2, b2, flag, out);
    }
}